// Round 1
// baseline (19165.948 us; speedup 1.0000x reference)
//
#include <hip/hip_runtime.h>
#include <hip/hip_cooperative_groups.h>
#include <stdint.h>

namespace cg = cooperative_groups;

#define T_STEPS 512
#define NB 64
#define NI 512
#define NH 1024
// gate-cols total = 4*NH = 4096

typedef __attribute__((ext_vector_type(8))) short short8;
typedef __attribute__((ext_vector_type(4))) float floatx4;
typedef __attribute__((ext_vector_type(16))) float floatx16;
typedef __attribute__((ext_vector_type(4))) unsigned short ushortx4;

__device__ __forceinline__ unsigned short f2bf(float f) {
  union { float f; uint32_t u; } v; v.f = f;
  return (unsigned short)((v.u + 0x7FFFu + ((v.u >> 16) & 1u)) >> 16);
}
__device__ __forceinline__ float bf2f(unsigned short s) {
  union { uint32_t u; float f; } v; v.u = ((uint32_t)s) << 16; return v.f;
}
__device__ __forceinline__ float sigmoid_f(float x) {
  return 1.0f / (1.0f + __expf(-x));
}
__device__ __forceinline__ float tanh_f(float x) {
  float xx = fminf(fmaxf(x, -15.0f), 15.0f);
  float e = __expf(2.0f * xx);
  return (e - 1.0f) / (e + 1.0f);
}

// ---------------- prep kernels ----------------

// X fp32 [T*B*I] -> bf16, 4 elems/thread, exact grid
__global__ void convert_x(const float* __restrict__ X, unsigned short* __restrict__ Xb) {
  int i = blockIdx.x * 256 + threadIdx.x;
  floatx4 x = ((const floatx4*)X)[i];
  ushortx4 o;
  o[0] = f2bf(x[0]); o[1] = f2bf(x[1]); o[2] = f2bf(x[2]); o[3] = f2bf(x[3]);
  ((ushortx4*)Xb)[i] = o;
}

// in [G][K][N] fp32 -> out [G][N][K] bf16 (n-major so K is contiguous)
__global__ void transpose_bf16(const float* __restrict__ in, unsigned short* __restrict__ outp,
                               int K, int N) {
  __shared__ float tile[64][65];
  int g = blockIdx.z;
  int k0 = blockIdx.x * 64, n0 = blockIdx.y * 64;
  int tx = threadIdx.x & 63, ty = threadIdx.x >> 6;
  const float* src = in + (size_t)g * K * N;
  unsigned short* dst = outp + (size_t)g * K * N;
#pragma unroll
  for (int i = 0; i < 16; i++) {
    int r = ty * 16 + i;
    tile[r][tx] = src[(size_t)(k0 + r) * N + n0 + tx];
  }
  __syncthreads();
#pragma unroll
  for (int i = 0; i < 16; i++) {
    int r = ty * 16 + i;
    dst[(size_t)(n0 + r) * K + k0 + tx] = f2bf(tile[tx][r]);
  }
}

// bias = bi + bh (fp32), hbuf0 = bf16(h0)
__global__ void prep_small(const float* __restrict__ bi, const float* __restrict__ bh,
                           const float* __restrict__ h0, float* __restrict__ bias,
                           unsigned short* __restrict__ hbuf0) {
  int i = blockIdx.x * 256 + threadIdx.x;
  if (i < 4 * NH) bias[i] = bi[i] + bh[i];
  if (i < NB * NH) hbuf0[i] = f2bf(h0[i]);
}

// ---------------- Zx GEMM: Zx[m][g*NH+n] = sum_k Xb[m][k]*WibT[g][n][k] + bias ----------------
// 128x128 tile, BK=32, 4 waves (2x2), 16x16x32 bf16 MFMA. M=32768, N=1024 per gate, K=512.
__global__ __launch_bounds__(256) void gemm_zx(
    const unsigned short* __restrict__ Xb,
    const unsigned short* __restrict__ WibT,
    const float* __restrict__ bias,
    unsigned short* __restrict__ Zx) {
  __shared__ __align__(16) unsigned short As[128][40];  // +8 pad
  __shared__ __align__(16) unsigned short Bs[128][40];
  const int g = blockIdx.z;
  const int m0 = blockIdx.x * 128;
  const int n0 = blockIdx.y * 128;
  const int tid = threadIdx.x;
  const int lane = tid & 63;
  const int wave = tid >> 6;
  const int wm = wave & 1, wn = wave >> 1;
  const int fr = lane & 15;            // frag row (m for A, n for B)
  const int fq = (lane >> 4) * 8;      // frag k offset

  const unsigned short* Bsrc = WibT + (size_t)g * NH * NI;

  floatx4 acc[4][4];
#pragma unroll
  for (int a = 0; a < 4; a++)
#pragma unroll
    for (int b = 0; b < 4; b++)
#pragma unroll
      for (int z = 0; z < 4; z++) acc[a][b][z] = 0.0f;

  for (int k0 = 0; k0 < NI; k0 += 32) {
#pragma unroll
    for (int it = 0; it < 2; it++) {
      int c = tid + it * 256;            // 0..511
      int row = c >> 2, kc = (c & 3) * 8;
      *(uint4*)(&As[row][kc]) = *(const uint4*)(Xb + (size_t)(m0 + row) * NI + k0 + kc);
      *(uint4*)(&Bs[row][kc]) = *(const uint4*)(Bsrc + (size_t)(n0 + row) * NI + k0 + kc);
    }
    __syncthreads();
    short8 af[4], bf[4];
#pragma unroll
    for (int ms = 0; ms < 4; ms++) af[ms] = *(const short8*)(&As[wm * 64 + ms * 16 + fr][fq]);
#pragma unroll
    for (int ns = 0; ns < 4; ns++) bf[ns] = *(const short8*)(&Bs[wn * 64 + ns * 16 + fr][fq]);
#pragma unroll
    for (int ms = 0; ms < 4; ms++)
#pragma unroll
      for (int ns = 0; ns < 4; ns++)
        acc[ms][ns] = __builtin_amdgcn_mfma_f32_16x16x32_bf16(af[ms], bf[ns], acc[ms][ns], 0, 0, 0);
    __syncthreads();
  }

  // C/D layout (16x16, verified): col = lane&15, row = (lane>>4)*4 + reg
#pragma unroll
  for (int ns = 0; ns < 4; ns++) {
    int col = n0 + wn * 64 + ns * 16 + fr;
    float bs = bias[g * NH + col];
#pragma unroll
    for (int ms = 0; ms < 4; ms++) {
#pragma unroll
      for (int r = 0; r < 4; r++) {
        int m = m0 + wm * 64 + ms * 16 + (lane >> 4) * 4 + r;
        Zx[(size_t)m * 4096 + (size_t)g * NH + col] = f2bf(acc[ms][ns][r] + bs);
      }
    }
  }
}

// ---------------- persistent recurrent kernel ----------------
// 128 blocks x 128 threads (2 waves). Block bk owns h-cols [bk*8, bk*8+8) => 32 gate-cols.
// Wh slice pre-swizzled into LDS as 32x32x16 MFMA B-fragments (64 KB), resident all steps.
// Per step: z = Zx_t + h @ WhSlice (MFMA fp32 acc), gates via shfl_xor quad exchange,
// c in regs (4x duplicated across gate-quad), h broadcast via double-buffered bf16 hbuf,
// one grid.sync per step.
__global__ __launch_bounds__(128, 1) void lstm_persist(
    const unsigned short* __restrict__ Zx,
    const unsigned short* __restrict__ WhT,   // [4][NH(n)][NH(k)] bf16
    const float* __restrict__ c0,
    unsigned short* __restrict__ hbuf,        // 2 x NB x NH bf16
    float* __restrict__ out) {
  cg::grid_group grid = cg::this_grid();
  __shared__ __align__(16) unsigned short bfr[64 * 64 * 8];  // [kk][lane][8] = 64 KB

  const int bk = blockIdx.x;
  const int j0 = bk * 8;
  const int tid = threadIdx.x;
  const int lane = tid & 63;
  const int wm = tid >> 6;        // wave = batch half (m-tile of 32)
  const int nl = lane & 31;       // MFMA col n (0..31): gate g0 = n>>3, h-col jj = n&7
  const int g0 = nl >> 3;
  const int jj = nl & 7;
  const int half = lane >> 5;

  // Fill B fragments: B[k][n] = Wh[g][k][j0+jj] = WhT[g][j0+jj][k]
  // frag layout: n = lane&31, k = kk*16 + (lane>>5)*8 + j
  for (int i = 0; i < 32; i++) {
    int f = tid + i * 128;        // 0..4095 = kk*64 + lane
    int fl = f & 63, kk = f >> 6;
    int n = fl & 31;
    size_t wrow = (size_t)((n >> 3) * NH + j0 + (n & 7));
    int kb = kk * 16 + (fl >> 5) * 8;
    uint4 v = *(const uint4*)(WhT + wrow * NH + kb);
    *(uint4*)(&bfr[(size_t)f * 8]) = v;
  }

  // c state in C/D layout: row = (r&3) + 8*(r>>2) + 4*half  (rows within 32-tile)
  float creg[16];
  int brow[16];
#pragma unroll
  for (int r = 0; r < 16; r++) {
    brow[r] = wm * 32 + (r & 3) + 8 * (r >> 2) + 4 * half;
    creg[r] = c0[(size_t)brow[r] * NH + j0 + jj];
  }
  __syncthreads();

  const int hsz = NB * NH;
  for (int t = 0; t < T_STEPS; t++) {
    const unsigned short* hin = hbuf + (size_t)(t & 1) * hsz;
    unsigned short* hout = hbuf + (size_t)((t + 1) & 1) * hsz;

    // prefetch this lane's Zx (own gate g0 only; quad exchange brings the rest)
    float zx[16];
    {
      const unsigned short* zbase = Zx + (size_t)t * NB * 4096 + (size_t)g0 * NH + j0 + jj;
#pragma unroll
      for (int r = 0; r < 16; r++) zx[r] = bf2f(zbase[(size_t)brow[r] * 4096]);
    }

    floatx16 acc0, acc1;
#pragma unroll
    for (int z = 0; z < 16; z++) { acc0[z] = 0.0f; acc1[z] = 0.0f; }

    // A frag: m = lane&31 (batch within half), k = kk*16 + half*8 + j
    const unsigned short* ap = hin + (size_t)(wm * 32 + nl) * NH + half * 8;
#pragma unroll
    for (int kk = 0; kk < 64; kk += 2) {
      short8 a0 = *(const short8*)(ap + kk * 16);
      short8 b0 = *(const short8*)(&bfr[(size_t)(kk * 64 + lane) * 8]);
      acc0 = __builtin_amdgcn_mfma_f32_32x32x16_bf16(a0, b0, acc0, 0, 0, 0);
      short8 a1 = *(const short8*)(ap + (kk + 1) * 16);
      short8 b1 = *(const short8*)(&bfr[(size_t)((kk + 1) * 64 + lane) * 8]);
      acc1 = __builtin_amdgcn_mfma_f32_32x32x16_bf16(a1, b1, acc1, 0, 0, 0);
    }
#pragma unroll
    for (int z = 0; z < 16; z++) acc0[z] += acc1[z];

    // epilogue: gather all 4 gates across the quad {l, l^8, l^16, l^24}
#pragma unroll
    for (int r = 0; r < 16; r++) {
      float z0 = acc0[r] + zx[r];          // gate g0
      float z1 = __shfl_xor(z0, 8);        // gate g0^1
      float z2 = __shfl_xor(z0, 16);       // gate g0^2
      float z3 = __shfl_xor(z1, 16);       // gate g0^3
      bool bb0 = (g0 & 1) != 0, bb1 = (g0 & 2) != 0;
      float zf = bb1 ? (bb0 ? z3 : z2) : (bb0 ? z1 : z0);  // zq[g0]
      float zi = bb1 ? (bb0 ? z2 : z3) : (bb0 ? z0 : z1);  // zq[1^g0]
      float zg = bb1 ? (bb0 ? z1 : z0) : (bb0 ? z3 : z2);  // zq[2^g0]
      float zo = bb1 ? (bb0 ? z0 : z1) : (bb0 ? z2 : z3);  // zq[3^g0]
      float fg = sigmoid_f(zf);
      float ig = sigmoid_f(zi);
      float gg = tanh_f(zg);
      float og = sigmoid_f(zo);
      float c = fg * creg[r] + ig * gg;
      creg[r] = c;
      float h = og * tanh_f(c);
      if (g0 == 0) {  // one writer per (b, j) quad
        size_t oidx = (size_t)brow[r] * NH + j0 + jj;
        out[(size_t)t * hsz + oidx] = h;
        hout[oidx] = f2bf(h);
        if (t == T_STEPS - 1) out[(size_t)T_STEPS * hsz + oidx] = h;  // h_n
      }
    }
    __threadfence();   // release h stores (cross-XCD)
    grid.sync();
    __threadfence();   // acquire before reading other blocks' h
  }

  // c_n
  if (g0 == 0) {
#pragma unroll
    for (int r = 0; r < 16; r++)
      out[(size_t)T_STEPS * NB * NH + NB * NH + (size_t)brow[r] * NH + j0 + jj] = creg[r];
  }
}

// ---------------- host launcher ----------------
extern "C" void kernel_launch(void* const* d_in, const int* in_sizes, int n_in,
                              void* d_out, int out_size, void* d_ws, size_t ws_size,
                              hipStream_t stream) {
  const float* X  = (const float*)d_in[0];
  const float* h0 = (const float*)d_in[1];
  const float* c0 = (const float*)d_in[2];
  const float* Wi = (const float*)d_in[3];
  const float* Wh = (const float*)d_in[4];
  const float* bi = (const float*)d_in[5];
  const float* bh = (const float*)d_in[6];
  float* out = (float*)d_out;

  uint8_t* ws = (uint8_t*)d_ws;
  size_t off = 0;
  auto alloc = [&](size_t bytes) -> void* {
    void* p = ws + off;
    off += (bytes + 255) & ~(size_t)255;
    return p;
  };
  unsigned short* Zx   = (unsigned short*)alloc((size_t)T_STEPS * NB * 4096 * 2);  // 268 MB
  unsigned short* Xb   = (unsigned short*)alloc((size_t)T_STEPS * NB * NI * 2);    // 33.6 MB
  unsigned short* WibT = (unsigned short*)alloc((size_t)4 * NH * NI * 2);          // 4.2 MB
  unsigned short* WhT  = (unsigned short*)alloc((size_t)4 * NH * NH * 2);          // 8.4 MB
  float* bias          = (float*)alloc((size_t)4 * NH * 4);
  unsigned short* hbuf = (unsigned short*)alloc((size_t)2 * NB * NH * 2);

  if (off > ws_size) {
    // unmistakable sentinel: ws too small
    hipMemsetAsync(d_out, 0x7F, (size_t)out_size * 4, stream);
    return;
  }

  convert_x<<<16384, 256, 0, stream>>>(X, Xb);
  transpose_bf16<<<dim3(8, 16, 4), 256, 0, stream>>>(Wi, WibT, NI, NH);
  transpose_bf16<<<dim3(16, 16, 4), 256, 0, stream>>>(Wh, WhT, NH, NH);
  prep_small<<<256, 256, 0, stream>>>(bi, bh, h0, bias, hbuf);
  gemm_zx<<<dim3(256, 8, 4), 256, 0, stream>>>(Xb, WibT, bias, Zx);

  void* args[] = {(void*)&Zx, (void*)&WhT, (void*)&c0, (void*)&hbuf, (void*)&out};
  hipLaunchCooperativeKernel(lstm_persist, dim3(128), dim3(128), args, 0, stream);
}

// Round 2
// 12829.544 us; speedup vs baseline: 1.4939x; 1.4939x over previous
//
#include <hip/hip_runtime.h>
#include <stdint.h>

#define T_STEPS 512
#define NB 64
#define NI 512
#define NH 1024
#define NBLK 128
// gate-cols total = 4*NH = 4096

typedef __attribute__((ext_vector_type(8))) short short8;
typedef __attribute__((ext_vector_type(4))) float floatx4;
typedef __attribute__((ext_vector_type(16))) float floatx16;
typedef __attribute__((ext_vector_type(4))) unsigned short ushortx4;

__device__ __forceinline__ unsigned short f2bf(float f) {
  union { float f; uint32_t u; } v; v.f = f;
  return (unsigned short)((v.u + 0x7FFFu + ((v.u >> 16) & 1u)) >> 16);
}
__device__ __forceinline__ float bf2f(unsigned short s) {
  union { uint32_t u; float f; } v; v.u = ((uint32_t)s) << 16; return v.f;
}
__device__ __forceinline__ float sigmoid_f(float x) {
  return 1.0f / (1.0f + __expf(-x));
}
__device__ __forceinline__ float tanh_f(float x) {
  float xx = fminf(fmaxf(x, -15.0f), 15.0f);
  float e = __expf(2.0f * xx);
  return (e - 1.0f) / (e + 1.0f);
}

// ---------------- prep kernels ----------------

// X fp32 [T*B*I] -> bf16, 4 elems/thread, exact grid
__global__ void convert_x(const float* __restrict__ X, unsigned short* __restrict__ Xb) {
  int i = blockIdx.x * 256 + threadIdx.x;
  floatx4 x = ((const floatx4*)X)[i];
  ushortx4 o;
  o[0] = f2bf(x[0]); o[1] = f2bf(x[1]); o[2] = f2bf(x[2]); o[3] = f2bf(x[3]);
  ((ushortx4*)Xb)[i] = o;
}

// in [G][K][N] fp32 -> out [G][N][K] bf16 (n-major so K is contiguous)
__global__ void transpose_bf16(const float* __restrict__ in, unsigned short* __restrict__ outp,
                               int K, int N) {
  __shared__ float tile[64][65];
  int g = blockIdx.z;
  int k0 = blockIdx.x * 64, n0 = blockIdx.y * 64;
  int tx = threadIdx.x & 63, ty = threadIdx.x >> 6;
  const float* src = in + (size_t)g * K * N;
  unsigned short* dst = outp + (size_t)g * K * N;
#pragma unroll
  for (int i = 0; i < 16; i++) {
    int r = ty * 16 + i;
    tile[r][tx] = src[(size_t)(k0 + r) * N + n0 + tx];
  }
  __syncthreads();
#pragma unroll
  for (int i = 0; i < 16; i++) {
    int r = ty * 16 + i;
    dst[(size_t)(n0 + r) * K + k0 + tx] = f2bf(tile[tx][r]);
  }
}

// bias = bi + bh (fp32), hbuf0 = bf16(h0), zero barrier counter
__global__ void prep_small(const float* __restrict__ bi, const float* __restrict__ bh,
                           const float* __restrict__ h0, float* __restrict__ bias,
                           unsigned short* __restrict__ hbuf0, unsigned* __restrict__ barcnt) {
  int i = blockIdx.x * 256 + threadIdx.x;
  if (i == 0) *barcnt = 0u;
  if (i < 4 * NH) bias[i] = bi[i] + bh[i];
  if (i < NB * NH) hbuf0[i] = f2bf(h0[i]);
}

// ---------------- Zx GEMM: Zx[m][g*NH+n] = sum_k Xb[m][k]*WibT[g][n][k] + bias ----------------
// 128x128 tile, BK=32, 4 waves (2x2), 16x16x32 bf16 MFMA. M=32768, N=1024 per gate, K=512.
__global__ __launch_bounds__(256) void gemm_zx(
    const unsigned short* __restrict__ Xb,
    const unsigned short* __restrict__ WibT,
    const float* __restrict__ bias,
    unsigned short* __restrict__ Zx) {
  __shared__ __align__(16) unsigned short As[128][40];  // +8 pad
  __shared__ __align__(16) unsigned short Bs[128][40];
  const int g = blockIdx.z;
  const int m0 = blockIdx.x * 128;
  const int n0 = blockIdx.y * 128;
  const int tid = threadIdx.x;
  const int lane = tid & 63;
  const int wave = tid >> 6;
  const int wm = wave & 1, wn = wave >> 1;
  const int fr = lane & 15;            // frag row (m for A, n for B)
  const int fq = (lane >> 4) * 8;      // frag k offset

  const unsigned short* Bsrc = WibT + (size_t)g * NH * NI;

  floatx4 acc[4][4];
#pragma unroll
  for (int a = 0; a < 4; a++)
#pragma unroll
    for (int b = 0; b < 4; b++)
#pragma unroll
      for (int z = 0; z < 4; z++) acc[a][b][z] = 0.0f;

  for (int k0 = 0; k0 < NI; k0 += 32) {
#pragma unroll
    for (int it = 0; it < 2; it++) {
      int c = tid + it * 256;            // 0..511
      int row = c >> 2, kc = (c & 3) * 8;
      *(uint4*)(&As[row][kc]) = *(const uint4*)(Xb + (size_t)(m0 + row) * NI + k0 + kc);
      *(uint4*)(&Bs[row][kc]) = *(const uint4*)(Bsrc + (size_t)(n0 + row) * NI + k0 + kc);
    }
    __syncthreads();
    short8 af[4], bf[4];
#pragma unroll
    for (int ms = 0; ms < 4; ms++) af[ms] = *(const short8*)(&As[wm * 64 + ms * 16 + fr][fq]);
#pragma unroll
    for (int ns = 0; ns < 4; ns++) bf[ns] = *(const short8*)(&Bs[wn * 64 + ns * 16 + fr][fq]);
#pragma unroll
    for (int ms = 0; ms < 4; ms++)
#pragma unroll
      for (int ns = 0; ns < 4; ns++)
        acc[ms][ns] = __builtin_amdgcn_mfma_f32_16x16x32_bf16(af[ms], bf[ns], acc[ms][ns], 0, 0, 0);
    __syncthreads();
  }

  // C/D layout (16x16, verified): col = lane&15, row = (lane>>4)*4 + reg
#pragma unroll
  for (int ns = 0; ns < 4; ns++) {
    int col = n0 + wn * 64 + ns * 16 + fr;
    float bs = bias[g * NH + col];
#pragma unroll
    for (int ms = 0; ms < 4; ms++) {
#pragma unroll
      for (int r = 0; r < 4; r++) {
        int m = m0 + wm * 64 + ms * 16 + (lane >> 4) * 4 + r;
        Zx[(size_t)m * 4096 + (size_t)g * NH + col] = f2bf(acc[ms][ns][r] + bs);
      }
    }
  }
}

// ---------------- lightweight grid barrier ----------------
// Monotonic counter, one arrival per block, relaxed agent-scope atomics,
// __threadfence() release/acquire for cross-XCD h visibility.
__device__ __forceinline__ void grid_barrier(unsigned* cnt, unsigned target, int tid) {
  __threadfence();   // release: each thread's h stores reach device scope
  __syncthreads();   // all threads of block fenced
  if (tid == 0) {
    __hip_atomic_fetch_add(cnt, 1u, __ATOMIC_RELAXED, __HIP_MEMORY_SCOPE_AGENT);
    while (__hip_atomic_load(cnt, __ATOMIC_RELAXED, __HIP_MEMORY_SCOPE_AGENT) < target)
      __builtin_amdgcn_s_sleep(2);
  }
  __syncthreads();
  __threadfence();   // acquire: invalidate stale cache before reading other blocks' h
}

// ---------------- persistent recurrent kernel ----------------
// 128 blocks x 128 threads (2 waves). Block bk owns h-cols [bk*8, bk*8+8) => 32 gate-cols.
// Wh slice pre-swizzled into LDS as 32x32x16 MFMA B-fragments (64 KB), resident all steps.
// Per step: z = Zx_t + h @ WhSlice (MFMA fp32 acc), gates via shfl_xor quad exchange,
// c in regs (4x duplicated across gate-quad), h broadcast via double-buffered bf16 hbuf,
// hand-rolled barrier per step (cg::grid.sync measured at ~35 us/step — Round 1).
__global__ __launch_bounds__(128, 1) void lstm_persist(
    const unsigned short* __restrict__ Zx,
    const unsigned short* __restrict__ WhT,   // [4][NH(n)][NH(k)] bf16
    const float* __restrict__ c0,
    unsigned short* __restrict__ hbuf,        // 2 x NB x NH bf16
    unsigned* __restrict__ barcnt,
    float* __restrict__ out) {
  __shared__ __align__(16) unsigned short bfr[64 * 64 * 8];  // [kk][lane][8] = 64 KB

  const int bk = blockIdx.x;
  const int j0 = bk * 8;
  const int tid = threadIdx.x;
  const int lane = tid & 63;
  const int wm = tid >> 6;        // wave = batch half (m-tile of 32)
  const int nl = lane & 31;       // MFMA col n (0..31): gate g0 = n>>3, h-col jj = n&7
  const int g0 = nl >> 3;
  const int jj = nl & 7;
  const int half = lane >> 5;

  // Fill B fragments: B[k][n] = Wh[g][k][j0+jj] = WhT[g][j0+jj][k]
  // frag layout: n = lane&31, k = kk*16 + (lane>>5)*8 + j
  for (int i = 0; i < 32; i++) {
    int f = tid + i * 128;        // 0..4095 = kk*64 + lane
    int fl = f & 63, kk = f >> 6;
    int n = fl & 31;
    size_t wrow = (size_t)((n >> 3) * NH + j0 + (n & 7));
    int kb = kk * 16 + (fl >> 5) * 8;
    uint4 v = *(const uint4*)(WhT + wrow * NH + kb);
    *(uint4*)(&bfr[(size_t)f * 8]) = v;
  }

  // c state in C/D layout: row = (r&3) + 8*(r>>2) + 4*half  (rows within 32-tile)
  float creg[16];
  int brow[16];
#pragma unroll
  for (int r = 0; r < 16; r++) {
    brow[r] = wm * 32 + (r & 3) + 8 * (r >> 2) + 4 * half;
    creg[r] = c0[(size_t)brow[r] * NH + j0 + jj];
  }
  __syncthreads();

  const int hsz = NB * NH;

  // Zx prefetch for t=0 (own gate g0 only; quad exchange brings the rest)
  float zx[16];
  {
    const unsigned short* zbase = Zx + (size_t)g0 * NH + j0 + jj;
#pragma unroll
    for (int r = 0; r < 16; r++) zx[r] = bf2f(zbase[(size_t)brow[r] * 4096]);
  }

  for (int t = 0; t < T_STEPS; t++) {
    const unsigned short* hin = hbuf + (size_t)(t & 1) * hsz;
    unsigned short* hout = hbuf + (size_t)((t + 1) & 1) * hsz;

    floatx16 acc0, acc1;
#pragma unroll
    for (int z = 0; z < 16; z++) { acc0[z] = 0.0f; acc1[z] = 0.0f; }

    // A frag: m = lane&31 (batch within half), k = kk*16 + half*8 + j
    const unsigned short* ap = hin + (size_t)(wm * 32 + nl) * NH + half * 8;
#pragma unroll
    for (int kk = 0; kk < 64; kk += 2) {
      short8 a0 = *(const short8*)(ap + kk * 16);
      short8 b0 = *(const short8*)(&bfr[(size_t)(kk * 64 + lane) * 8]);
      acc0 = __builtin_amdgcn_mfma_f32_32x32x16_bf16(a0, b0, acc0, 0, 0, 0);
      short8 a1 = *(const short8*)(ap + (kk + 1) * 16);
      short8 b1 = *(const short8*)(&bfr[(size_t)((kk + 1) * 64 + lane) * 8]);
      acc1 = __builtin_amdgcn_mfma_f32_32x32x16_bf16(a1, b1, acc1, 0, 0, 0);
    }
#pragma unroll
    for (int z = 0; z < 16; z++) acc0[z] += acc1[z];

    // Prefetch Zx for t+1 — overlaps the epilogue + barrier latency.
    float zxn[16];
    if (t + 1 < T_STEPS) {
      const unsigned short* zbase = Zx + (size_t)(t + 1) * (NB * 4096) + (size_t)g0 * NH + j0 + jj;
#pragma unroll
      for (int r = 0; r < 16; r++) zxn[r] = bf2f(zbase[(size_t)brow[r] * 4096]);
    }

    // epilogue: gather all 4 gates across the quad {l, l^8, l^16, l^24}
#pragma unroll
    for (int r = 0; r < 16; r++) {
      float z0 = acc0[r] + zx[r];          // gate g0
      float z1 = __shfl_xor(z0, 8);        // gate g0^1
      float z2 = __shfl_xor(z0, 16);       // gate g0^2
      float z3 = __shfl_xor(z1, 16);       // gate g0^3
      bool bb0 = (g0 & 1) != 0, bb1 = (g0 & 2) != 0;
      float zf = bb1 ? (bb0 ? z3 : z2) : (bb0 ? z1 : z0);  // zq[g0]
      float zi = bb1 ? (bb0 ? z2 : z3) : (bb0 ? z0 : z1);  // zq[1^g0]
      float zg = bb1 ? (bb0 ? z1 : z0) : (bb0 ? z3 : z2);  // zq[2^g0]
      float zo = bb1 ? (bb0 ? z0 : z1) : (bb0 ? z2 : z3);  // zq[3^g0]
      float fg = sigmoid_f(zf);
      float ig = sigmoid_f(zi);
      float gg = tanh_f(zg);
      float og = sigmoid_f(zo);
      float c = fg * creg[r] + ig * gg;
      creg[r] = c;
      float h = og * tanh_f(c);
      if (g0 == 0) {  // one writer per (b, j) quad
        size_t oidx = (size_t)brow[r] * NH + j0 + jj;
        out[(size_t)t * hsz + oidx] = h;
        hout[oidx] = f2bf(h);
        if (t == T_STEPS - 1) out[(size_t)T_STEPS * hsz + oidx] = h;  // h_n
      }
    }

    grid_barrier(barcnt, (unsigned)NBLK * (unsigned)(t + 1), tid);

#pragma unroll
    for (int r = 0; r < 16; r++) zx[r] = zxn[r];
  }

  // c_n
  if (g0 == 0) {
#pragma unroll
    for (int r = 0; r < 16; r++)
      out[(size_t)T_STEPS * NB * NH + NB * NH + (size_t)brow[r] * NH + j0 + jj] = creg[r];
  }
}

// ---------------- host launcher ----------------
extern "C" void kernel_launch(void* const* d_in, const int* in_sizes, int n_in,
                              void* d_out, int out_size, void* d_ws, size_t ws_size,
                              hipStream_t stream) {
  const float* X  = (const float*)d_in[0];
  const float* h0 = (const float*)d_in[1];
  const float* c0 = (const float*)d_in[2];
  const float* Wi = (const float*)d_in[3];
  const float* Wh = (const float*)d_in[4];
  const float* bi = (const float*)d_in[5];
  const float* bh = (const float*)d_in[6];
  float* out = (float*)d_out;

  uint8_t* ws = (uint8_t*)d_ws;
  size_t off = 0;
  auto alloc = [&](size_t bytes) -> void* {
    void* p = ws + off;
    off += (bytes + 255) & ~(size_t)255;
    return p;
  };
  unsigned short* Zx   = (unsigned short*)alloc((size_t)T_STEPS * NB * 4096 * 2);  // 268 MB
  unsigned short* Xb   = (unsigned short*)alloc((size_t)T_STEPS * NB * NI * 2);    // 33.6 MB
  unsigned short* WibT = (unsigned short*)alloc((size_t)4 * NH * NI * 2);          // 4.2 MB
  unsigned short* WhT  = (unsigned short*)alloc((size_t)4 * NH * NH * 2);          // 8.4 MB
  float* bias          = (float*)alloc((size_t)4 * NH * 4);
  unsigned short* hbuf = (unsigned short*)alloc((size_t)2 * NB * NH * 2);
  unsigned* barcnt     = (unsigned*)alloc(256);

  if (off > ws_size) {
    // unmistakable sentinel: ws too small
    hipMemsetAsync(d_out, 0x7F, (size_t)out_size * 4, stream);
    return;
  }

  convert_x<<<16384, 256, 0, stream>>>(X, Xb);
  transpose_bf16<<<dim3(8, 16, 4), 256, 0, stream>>>(Wi, WibT, NI, NH);
  transpose_bf16<<<dim3(16, 16, 4), 256, 0, stream>>>(Wh, WhT, NH, NH);
  prep_small<<<256, 256, 0, stream>>>(bi, bh, h0, bias, hbuf, barcnt);
  gemm_zx<<<dim3(256, 8, 4), 256, 0, stream>>>(Xb, WibT, bias, Zx);

  lstm_persist<<<dim3(NBLK), dim3(128), 0, stream>>>(Zx, WhT, c0, hbuf, barcnt, out);
}

// Round 3
// 8432.161 us; speedup vs baseline: 2.2730x; 1.5215x over previous
//
#include <hip/hip_runtime.h>
#include <stdint.h>

#define T_STEPS 512
#define NB 64
#define NI 512
#define NH 1024
#define NBLK 128
// gate-cols total = 4*NH = 4096

typedef __attribute__((ext_vector_type(8))) short short8;
typedef __attribute__((ext_vector_type(4))) float floatx4;
typedef __attribute__((ext_vector_type(16))) float floatx16;
typedef __attribute__((ext_vector_type(4))) unsigned short ushortx4;

__device__ __forceinline__ unsigned short f2bf(float f) {
  union { float f; uint32_t u; } v; v.f = f;
  return (unsigned short)((v.u + 0x7FFFu + ((v.u >> 16) & 1u)) >> 16);
}
__device__ __forceinline__ float bf2f(unsigned short s) {
  union { uint32_t u; float f; } v; v.u = ((uint32_t)s) << 16; return v.f;
}
__device__ __forceinline__ float sigmoid_f(float x) {
  return 1.0f / (1.0f + __expf(-x));
}
__device__ __forceinline__ float tanh_f(float x) {
  float xx = fminf(fmaxf(x, -15.0f), 15.0f);
  float e = __expf(2.0f * xx);
  return (e - 1.0f) / (e + 1.0f);
}

// ---------------- prep kernels ----------------

// X fp32 [T*B*I] -> bf16, 4 elems/thread, exact grid
__global__ void convert_x(const float* __restrict__ X, unsigned short* __restrict__ Xb) {
  int i = blockIdx.x * 256 + threadIdx.x;
  floatx4 x = ((const floatx4*)X)[i];
  ushortx4 o;
  o[0] = f2bf(x[0]); o[1] = f2bf(x[1]); o[2] = f2bf(x[2]); o[3] = f2bf(x[3]);
  ((ushortx4*)Xb)[i] = o;
}

// in [G][K][N] fp32 -> out [G][N][K] bf16 (n-major so K is contiguous)
__global__ void transpose_bf16(const float* __restrict__ in, unsigned short* __restrict__ outp,
                               int K, int N) {
  __shared__ float tile[64][65];
  int g = blockIdx.z;
  int k0 = blockIdx.x * 64, n0 = blockIdx.y * 64;
  int tx = threadIdx.x & 63, ty = threadIdx.x >> 6;
  const float* src = in + (size_t)g * K * N;
  unsigned short* dst = outp + (size_t)g * K * N;
#pragma unroll
  for (int i = 0; i < 16; i++) {
    int r = ty * 16 + i;
    tile[r][tx] = src[(size_t)(k0 + r) * N + n0 + tx];
  }
  __syncthreads();
#pragma unroll
  for (int i = 0; i < 16; i++) {
    int r = ty * 16 + i;
    dst[(size_t)(n0 + r) * K + k0 + tx] = f2bf(tile[tx][r]);
  }
}

// bias = bi + bh (fp32), hbuf0 = bf16(h0), zero barrier flags
__global__ void prep_small(const float* __restrict__ bi, const float* __restrict__ bh,
                           const float* __restrict__ h0, float* __restrict__ bias,
                           unsigned short* __restrict__ hbuf0, unsigned* __restrict__ flags) {
  int i = blockIdx.x * 256 + threadIdx.x;
  if (i < NBLK) flags[i * 32] = 0u;   // 128-B spaced flags
  if (i < 4 * NH) bias[i] = bi[i] + bh[i];
  if (i < NB * NH) hbuf0[i] = f2bf(h0[i]);
}

// ---------------- Zx GEMM: Zx[m][g*NH+n] = sum_k Xb[m][k]*WibT[g][n][k] + bias ----------------
// 128x128 tile, BK=32, 4 waves (2x2), 16x16x32 bf16 MFMA. M=32768, N=1024 per gate, K=512.
__global__ __launch_bounds__(256) void gemm_zx(
    const unsigned short* __restrict__ Xb,
    const unsigned short* __restrict__ WibT,
    const float* __restrict__ bias,
    unsigned short* __restrict__ Zx) {
  __shared__ __align__(16) unsigned short As[128][40];  // +8 pad
  __shared__ __align__(16) unsigned short Bs[128][40];
  const int g = blockIdx.z;
  const int m0 = blockIdx.x * 128;
  const int n0 = blockIdx.y * 128;
  const int tid = threadIdx.x;
  const int lane = tid & 63;
  const int wave = tid >> 6;
  const int wm = wave & 1, wn = wave >> 1;
  const int fr = lane & 15;            // frag row (m for A, n for B)
  const int fq = (lane >> 4) * 8;      // frag k offset

  const unsigned short* Bsrc = WibT + (size_t)g * NH * NI;

  floatx4 acc[4][4];
#pragma unroll
  for (int a = 0; a < 4; a++)
#pragma unroll
    for (int b = 0; b < 4; b++)
#pragma unroll
      for (int z = 0; z < 4; z++) acc[a][b][z] = 0.0f;

  for (int k0 = 0; k0 < NI; k0 += 32) {
#pragma unroll
    for (int it = 0; it < 2; it++) {
      int c = tid + it * 256;            // 0..511
      int row = c >> 2, kc = (c & 3) * 8;
      *(uint4*)(&As[row][kc]) = *(const uint4*)(Xb + (size_t)(m0 + row) * NI + k0 + kc);
      *(uint4*)(&Bs[row][kc]) = *(const uint4*)(Bsrc + (size_t)(n0 + row) * NI + k0 + kc);
    }
    __syncthreads();
    short8 af[4], bf[4];
#pragma unroll
    for (int ms = 0; ms < 4; ms++) af[ms] = *(const short8*)(&As[wm * 64 + ms * 16 + fr][fq]);
#pragma unroll
    for (int ns = 0; ns < 4; ns++) bf[ns] = *(const short8*)(&Bs[wn * 64 + ns * 16 + fr][fq]);
#pragma unroll
    for (int ms = 0; ms < 4; ms++)
#pragma unroll
      for (int ns = 0; ns < 4; ns++)
        acc[ms][ns] = __builtin_amdgcn_mfma_f32_16x16x32_bf16(af[ms], bf[ns], acc[ms][ns], 0, 0, 0);
    __syncthreads();
  }

  // C/D layout (16x16, verified): col = lane&15, row = (lane>>4)*4 + reg
#pragma unroll
  for (int ns = 0; ns < 4; ns++) {
    int col = n0 + wn * 64 + ns * 16 + fr;
    float bs = bias[g * NH + col];
#pragma unroll
    for (int ms = 0; ms < 4; ms++) {
#pragma unroll
      for (int r = 0; r < 4; r++) {
        int m = m0 + wm * 64 + ms * 16 + (lane >> 4) * 4 + r;
        Zx[(size_t)m * 4096 + (size_t)g * NH + col] = f2bf(acc[ms][ns][r] + bs);
      }
    }
  }
}

// ---------------- persistent recurrent kernel ----------------
// 128 blocks x 128 threads (2 waves). Block bk owns h-cols [bk*8, bk*8+8) => 32 gate-cols.
// Wh slice pre-swizzled into LDS as 32x32x16 MFMA B-fragments (64 KB), resident all steps.
// Per step: z = Zx_t + h @ WhSlice (MFMA fp32 acc), gates via shfl_xor quad exchange,
// c in regs, h broadcast double-buffered in ws.
// Sync protocol (R3): contention-free flag barrier + hand-rolled coherence.
//   release: h stores are agent-scope write-through (sc0 sc1), s_waitcnt vmcnt(0),
//            then per-block flag := t+1 (own 128-B line, plain store — no RMW).
//   arrive:  every lane polls 2 of the 128 flags (agent-scope loads, bypass caches).
//   acquire: one buffer_inv sc0 sc1 (drop stale clean lines; refill from coherence pt).
// R1: cg::grid.sync = 36.9 us/step. R2: single-counter atomic barrier = 24.2 us/step
// (128 serialized cross-XCD RMWs + 2x full-L2 fence sweeps).
__global__ __launch_bounds__(128, 1) void lstm_persist(
    const unsigned short* __restrict__ Zx,
    const unsigned short* __restrict__ WhT,   // [4][NH(n)][NH(k)] bf16
    const float* __restrict__ c0,
    unsigned short* __restrict__ hbuf,        // 2 x NB x NH bf16
    unsigned* __restrict__ flags,             // NBLK x 32 dwords (128-B spaced)
    float* __restrict__ out) {
  __shared__ __align__(16) unsigned short bfr[64 * 64 * 8];  // [kk][lane][8] = 64 KB

  const int bk = blockIdx.x;
  const int j0 = bk * 8;
  const int tid = threadIdx.x;
  const int lane = tid & 63;
  const int wm = tid >> 6;        // wave = batch half (m-tile of 32)
  const int nl = lane & 31;       // MFMA col n (0..31): gate g0 = n>>3, h-col jj = n&7
  const int g0 = nl >> 3;
  const int jj = nl & 7;
  const int half = lane >> 5;

  // Fill B fragments: B[k][n] = Wh[g][k][j0+jj] = WhT[g][j0+jj][k]
  // frag layout: n = lane&31, k = kk*16 + (lane>>5)*8 + j
  for (int i = 0; i < 32; i++) {
    int f = tid + i * 128;        // 0..4095 = kk*64 + lane
    int fl = f & 63, kk = f >> 6;
    int n = fl & 31;
    size_t wrow = (size_t)((n >> 3) * NH + j0 + (n & 7));
    int kb = kk * 16 + (fl >> 5) * 8;
    uint4 v = *(const uint4*)(WhT + wrow * NH + kb);
    *(uint4*)(&bfr[(size_t)f * 8]) = v;
  }

  // c state in C/D layout: row = (r&3) + 8*(r>>2) + 4*half  (rows within 32-tile)
  float creg[16];
  int brow[16];
#pragma unroll
  for (int r = 0; r < 16; r++) {
    brow[r] = wm * 32 + (r & 3) + 8 * (r >> 2) + 4 * half;
    creg[r] = c0[(size_t)brow[r] * NH + j0 + jj];
  }
  __syncthreads();

  const int hsz = NB * NH;

  // poll addresses for this lane: flags lane and lane+64
  const unsigned* fp0 = flags + (size_t)lane * 32;
  const unsigned* fp1 = flags + (size_t)(lane + 64) * 32;

  // Zx prefetch for t=0 (own gate g0 only; quad exchange brings the rest)
  float zx[16];
  {
    const unsigned short* zbase = Zx + (size_t)g0 * NH + j0 + jj;
#pragma unroll
    for (int r = 0; r < 16; r++) zx[r] = bf2f(zbase[(size_t)brow[r] * 4096]);
  }

  for (int t = 0; t < T_STEPS; t++) {
    const unsigned short* hin = hbuf + (size_t)(t & 1) * hsz;
    unsigned short* hout = hbuf + (size_t)((t + 1) & 1) * hsz;

    floatx16 acc0, acc1;
#pragma unroll
    for (int z = 0; z < 16; z++) { acc0[z] = 0.0f; acc1[z] = 0.0f; }

    // A frag: m = lane&31 (batch within half), k = kk*16 + half*8 + j
    const unsigned short* ap = hin + (size_t)(wm * 32 + nl) * NH + half * 8;
#pragma unroll
    for (int kk = 0; kk < 64; kk += 2) {
      short8 a0 = *(const short8*)(ap + kk * 16);
      short8 b0 = *(const short8*)(&bfr[(size_t)(kk * 64 + lane) * 8]);
      acc0 = __builtin_amdgcn_mfma_f32_32x32x16_bf16(a0, b0, acc0, 0, 0, 0);
      short8 a1 = *(const short8*)(ap + (kk + 1) * 16);
      short8 b1 = *(const short8*)(&bfr[(size_t)((kk + 1) * 64 + lane) * 8]);
      acc1 = __builtin_amdgcn_mfma_f32_32x32x16_bf16(a1, b1, acc1, 0, 0, 0);
    }
#pragma unroll
    for (int z = 0; z < 16; z++) acc0[z] += acc1[z];

    // Prefetch Zx for t+1 — overlaps the epilogue + barrier latency.
    float zxn[16];
    if (t + 1 < T_STEPS) {
      const unsigned short* zbase = Zx + (size_t)(t + 1) * (NB * 4096) + (size_t)g0 * NH + j0 + jj;
#pragma unroll
      for (int r = 0; r < 16; r++) zxn[r] = bf2f(zbase[(size_t)brow[r] * 4096]);
    }

    // epilogue: gather all 4 gates across the quad {l, l^8, l^16, l^24}
#pragma unroll
    for (int r = 0; r < 16; r++) {
      float z0 = acc0[r] + zx[r];          // gate g0
      float z1 = __shfl_xor(z0, 8);        // gate g0^1
      float z2 = __shfl_xor(z0, 16);       // gate g0^2
      float z3 = __shfl_xor(z1, 16);       // gate g0^3
      bool bb0 = (g0 & 1) != 0, bb1 = (g0 & 2) != 0;
      float zf = bb1 ? (bb0 ? z3 : z2) : (bb0 ? z1 : z0);  // zq[g0]
      float zi = bb1 ? (bb0 ? z2 : z3) : (bb0 ? z0 : z1);  // zq[1^g0]
      float zg = bb1 ? (bb0 ? z1 : z0) : (bb0 ? z3 : z2);  // zq[2^g0]
      float zo = bb1 ? (bb0 ? z0 : z1) : (bb0 ? z2 : z3);  // zq[3^g0]
      float fg = sigmoid_f(zf);
      float ig = sigmoid_f(zi);
      float gg = tanh_f(zg);
      float og = sigmoid_f(zo);
      float c = fg * creg[r] + ig * gg;
      creg[r] = c;
      float h = og * tanh_f(c);
      if (g0 == 0) {  // one writer per (b, j) quad
        size_t oidx = (size_t)brow[r] * NH + j0 + jj;
        out[(size_t)t * hsz + oidx] = h;
        // agent-scope write-through: reaches coherence point, no wbl2 needed
        __hip_atomic_store(&hout[oidx], f2bf(h), __ATOMIC_RELAXED,
                           __HIP_MEMORY_SCOPE_AGENT);
        if (t == T_STEPS - 1) out[(size_t)T_STEPS * hsz + oidx] = h;  // h_n
      }
    }

    if (t + 1 < T_STEPS) {
      // ---- release ----
      asm volatile("s_waitcnt vmcnt(0)" ::: "memory");  // h stores at coherence point
      __syncthreads();                                   // both waves drained
      if (tid == 0)
        __hip_atomic_store(flags + (size_t)bk * 32, (unsigned)(t + 1),
                           __ATOMIC_RELAXED, __HIP_MEMORY_SCOPE_AGENT);
      // ---- arrive: poll 2 flags per lane, no contention (plain loads) ----
      unsigned tgt = (unsigned)(t + 1);
      while (__hip_atomic_load(fp0, __ATOMIC_RELAXED, __HIP_MEMORY_SCOPE_AGENT) < tgt)
        __builtin_amdgcn_s_sleep(1);
      while (__hip_atomic_load(fp1, __ATOMIC_RELAXED, __HIP_MEMORY_SCOPE_AGENT) < tgt)
        __builtin_amdgcn_s_sleep(1);
      // ---- acquire: drop stale clean lines (L1+L2); dirty lines unaffected ----
      asm volatile("buffer_inv sc0 sc1" ::: "memory");
    }

#pragma unroll
    for (int r = 0; r < 16; r++) zx[r] = zxn[r];
  }

  // c_n
  if (g0 == 0) {
#pragma unroll
    for (int r = 0; r < 16; r++)
      out[(size_t)T_STEPS * NB * NH + NB * NH + (size_t)brow[r] * NH + j0 + jj] = creg[r];
  }
}

// ---------------- host launcher ----------------
extern "C" void kernel_launch(void* const* d_in, const int* in_sizes, int n_in,
                              void* d_out, int out_size, void* d_ws, size_t ws_size,
                              hipStream_t stream) {
  const float* X  = (const float*)d_in[0];
  const float* h0 = (const float*)d_in[1];
  const float* c0 = (const float*)d_in[2];
  const float* Wi = (const float*)d_in[3];
  const float* Wh = (const float*)d_in[4];
  const float* bi = (const float*)d_in[5];
  const float* bh = (const float*)d_in[6];
  float* out = (float*)d_out;

  uint8_t* ws = (uint8_t*)d_ws;
  size_t off = 0;
  auto alloc = [&](size_t bytes) -> void* {
    void* p = ws + off;
    off += (bytes + 255) & ~(size_t)255;
    return p;
  };
  unsigned short* Zx   = (unsigned short*)alloc((size_t)T_STEPS * NB * 4096 * 2);  // 268 MB
  unsigned short* Xb   = (unsigned short*)alloc((size_t)T_STEPS * NB * NI * 2);    // 33.6 MB
  unsigned short* WibT = (unsigned short*)alloc((size_t)4 * NH * NI * 2);          // 4.2 MB
  unsigned short* WhT  = (unsigned short*)alloc((size_t)4 * NH * NH * 2);          // 8.4 MB
  float* bias          = (float*)alloc((size_t)4 * NH * 4);
  unsigned short* hbuf = (unsigned short*)alloc((size_t)2 * NB * NH * 2);
  unsigned* flags      = (unsigned*)alloc((size_t)NBLK * 32 * 4);                  // 16 KB

  if (off > ws_size) {
    // unmistakable sentinel: ws too small
    hipMemsetAsync(d_out, 0x7F, (size_t)out_size * 4, stream);
    return;
  }

  convert_x<<<16384, 256, 0, stream>>>(X, Xb);
  transpose_bf16<<<dim3(8, 16, 4), 256, 0, stream>>>(Wi, WibT, NI, NH);
  transpose_bf16<<<dim3(16, 16, 4), 256, 0, stream>>>(Wh, WhT, NH, NH);
  prep_small<<<256, 256, 0, stream>>>(bi, bh, h0, bias, hbuf, flags);
  gemm_zx<<<dim3(256, 8, 4), 256, 0, stream>>>(Xb, WibT, bias, Zx);

  lstm_persist<<<dim3(NBLK), dim3(128), 0, stream>>>(Zx, WhT, c0, hbuf, flags, out);
}